// Round 12
// baseline (289.855 us; speedup 1.0000x reference)
//
#include <hip/hip_runtime.h>
#include <stdint.h>

#define NN   4096
#define KIN  256
#define NH   8
#define FD   64
#define HFD  512
#define BI   16
#define JT   64
#define NC2  2
#define CH   (NN / NC2)     // 2048 j per chunk
#define NT2  (CH / JT)      // 32 tiles

typedef __attribute__((ext_vector_type(4))) float  floatx4;
typedef __attribute__((ext_vector_type(8))) short  short8;

__device__ __forceinline__ unsigned short f2bf_rne(float x) {
    uint32_t u = __float_as_uint(x);
    u += 0x7FFFu + ((u >> 16) & 1u);
    return (unsigned short)(u >> 16);
}
__device__ __forceinline__ float bf2f(unsigned short b) {
    return __uint_as_float(((uint32_t)b) << 16);
}
__device__ __forceinline__ uint32_t packtrunc(float lo, float hi) {
    return (__float_as_uint(hi) & 0xFFFF0000u) | (__float_as_uint(lo) >> 16);
}
__device__ __forceinline__ uint32_t bit2mask(uint32_t b, int n) {
    return (((b >> (2 * n)) & 1u) ? 0x0000FFFFu : 0u) |
           (((b >> (2 * n + 1)) & 1u) ? 0xFFFF0000u : 0u);
}

// ---- k0: h/W bf16 hi-lo split + adj -> 2 MiB bitmask ----
__global__ __launch_bounds__(256) void k0_prep(
        const float* __restrict__ hmat, const float* __restrict__ Wmat,
        const int* __restrict__ adj,
        unsigned short* __restrict__ h_hi, unsigned short* __restrict__ h_lo,
        unsigned short* __restrict__ wt_hi, unsigned short* __restrict__ wt_lo,
        uint32_t* __restrict__ bm) {
    const int bx = blockIdx.x, tid = threadIdx.x;
    if (bx < 1024) {
        const int e0 = (bx * 256 + tid) * 4;
        const float4 v = *reinterpret_cast<const float4*>(&hmat[e0]);
        ushort4 hi, lo;
        hi.x = f2bf_rne(v.x); lo.x = f2bf_rne(v.x - bf2f(hi.x));
        hi.y = f2bf_rne(v.y); lo.y = f2bf_rne(v.y - bf2f(hi.y));
        hi.z = f2bf_rne(v.z); lo.z = f2bf_rne(v.z - bf2f(hi.z));
        hi.w = f2bf_rne(v.w); lo.w = f2bf_rne(v.w - bf2f(hi.w));
        *reinterpret_cast<ushort4*>(&h_hi[e0]) = hi;
        *reinterpret_cast<ushort4*>(&h_lo[e0]) = lo;
    } else if (bx < 1536) {
        const int c = bx - 1024;
        const float v = Wmat[(size_t)tid * HFD + c];
        const unsigned short hi = f2bf_rne(v);
        const unsigned short lo = f2bf_rne(v - bf2f(hi));
        wt_hi[c * KIN + tid] = hi;
        wt_lo[c * KIN + tid] = lo;
    } else {
        const int widx = (bx - 1536) * 256 + tid;
        const size_t base = (size_t)widx * 32;
        uint32_t m = 0;
        #pragma unroll
        for (int u = 0; u < 8; ++u) {
            const int4 a = *reinterpret_cast<const int4*>(&adj[base + u * 4]);
            m |= (a.x ? 1u : 0u) << (u * 4 + 0);
            m |= (a.y ? 1u : 0u) << (u * 4 + 1);
            m |= (a.z ? 1u : 0u) << (u * 4 + 2);
            m |= (a.w ? 1u : 0u) << (u * 4 + 3);
        }
        bm[widx] = m;
    }
}

// ---- k1: Wh via MFMA hi/lo split; whbT + e tables ----
__global__ __launch_bounds__(256) void k1_front(
        const unsigned short* __restrict__ h_hi, const unsigned short* __restrict__ h_lo,
        const unsigned short* __restrict__ wt_hi, const unsigned short* __restrict__ wt_lo,
        const float* __restrict__ a_src, const float* __restrict__ a_dst,
        unsigned short* __restrict__ whbT,
        float* __restrict__ esrcT, float* __restrict__ edstT) {
    const int tid  = threadIdx.x;
    const int w    = tid >> 6;
    const int lane = tid & 63;
    const int g = lane >> 4, lr = lane & 15;
    const int n0  = blockIdx.x * 64;
    const int hd  = blockIdx.y;
    const int hf0 = hd * FD;
    const int row = n0 + w * 16 + lr;
    floatx4 acc[4] = {};
    #pragma unroll
    for (int k0 = 0; k0 < KIN; k0 += 32) {
        const short8 ahi = *reinterpret_cast<const short8*>(&h_hi[(size_t)row * KIN + k0 + g * 8]);
        const short8 alo = *reinterpret_cast<const short8*>(&h_lo[(size_t)row * KIN + k0 + g * 8]);
        #pragma unroll
        for (int ni = 0; ni < 4; ++ni) {
            const size_t bo = (size_t)(hf0 + ni * 16 + lr) * KIN + k0 + g * 8;
            const short8 bhi = *reinterpret_cast<const short8*>(&wt_hi[bo]);
            const short8 blo = *reinterpret_cast<const short8*>(&wt_lo[bo]);
            acc[ni] = __builtin_amdgcn_mfma_f32_16x16x32_bf16(ahi, bhi, acc[ni], 0, 0, 0);
            acc[ni] = __builtin_amdgcn_mfma_f32_16x16x32_bf16(ahi, blo, acc[ni], 0, 0, 0);
            acc[ni] = __builtin_amdgcn_mfma_f32_16x16x32_bf16(alo, bhi, acc[ni], 0, 0, 0);
        }
    }
    #pragma unroll
    for (int ni = 0; ni < 4; ++ni) {
        const int hf = hf0 + ni * 16 + lr;
        ushort4 o;
        o.x = f2bf_rne(acc[ni][0]); o.y = f2bf_rne(acc[ni][1]);
        o.z = f2bf_rne(acc[ni][2]); o.w = f2bf_rne(acc[ni][3]);
        *reinterpret_cast<ushort4*>(&whbT[(size_t)hf * NN + n0 + w * 16 + g * 4]) = o;
    }
    float asv[4], adv[4];
    #pragma unroll
    for (int ni = 0; ni < 4; ++ni) {
        asv[ni] = a_src[hf0 + ni * 16 + lr];
        adv[ni] = a_dst[hf0 + ni * 16 + lr];
    }
    #pragma unroll
    for (int r = 0; r < 4; ++r) {
        float ps = 0.f, pd = 0.f;
        #pragma unroll
        for (int ni = 0; ni < 4; ++ni) { ps += acc[ni][r] * asv[ni]; pd += acc[ni][r] * adv[ni]; }
        #pragma unroll
        for (int off = 1; off < 16; off <<= 1) {
            ps += __shfl_xor(ps, off, 64);
            pd += __shfl_xor(pd, off, 64);
        }
        if (lr == 0) {
            esrcT[hd * NN + n0 + w * 16 + g * 4 + r] = ps;
            edstT[hd * NN + n0 + w * 16 + g * 4 + r] = pd;
        }
    }
}

// ---- k2: per-head max(e_dst) and the four exp tables ----
__global__ __launch_bounds__(256) void k2_tables(
        const float* __restrict__ esrcT, const float* __restrict__ edstT,
        float* __restrict__ es1T, float* __restrict__ es2T,
        float* __restrict__ ed1T, float* __restrict__ ed2T) {
    __shared__ float red[256];
    const int hd = blockIdx.x, tid = threadIdx.x;
    float m = -1e30f;
    for (int n = tid; n < NN; n += 256) m = fmaxf(m, edstT[hd * NN + n]);
    red[tid] = m;
    __syncthreads();
    for (int s = 128; s > 0; s >>= 1) {
        if (tid < s) red[tid] = fmaxf(red[tid], red[tid + s]);
        __syncthreads();
    }
    const float maxd = red[0];
    for (int n = tid; n < NN; n += 256) {
        const float ed = edstT[hd * NN + n];
        ed1T[hd * NN + n] = __expf(ed);
        ed2T[hd * NN + n] = __expf(0.2f * ed);
        const float es = esrcT[hd * NN + n];
        const float t  = es + maxd;
        const float M  = fmaxf(t, 0.2f * t);
        es1T[hd * NN + n] = __expf(es - M);
        es2T[hd * NN + n] = __expf(0.2f * es - M);
    }
}

// ---- k3: NC=2 j-split, software-pipelined; bitmask LDS; partial num/den ----
__global__ __launch_bounds__(256, 4) void k3_attn(
        const uint32_t* __restrict__ bm, const unsigned short* __restrict__ whbT,
        const float* __restrict__ es1T, const float* __restrict__ es2T,
        const float* __restrict__ ed1T, const float* __restrict__ ed2T,
        float* __restrict__ numP, float* __restrict__ denP) {
    __shared__ uint32_t bmLds[BI * 65];     // 16 rows x 64 words, stride 65
    const int tid  = threadIdx.x;
    const int lane = tid & 63;
    const int wl   = tid >> 6;
    const int bx   = blockIdx.x;            // 1024 blocks
    // bijective decomposition with per-XCD jc + window stagger
    const int xcd  = bx & 7;
    const int r8   = bx >> 3;               // 0..127
    const int jc   = xcd >> 2;              // 0/1, constant per XCD
    const int l4   = xcd & 3;
    const int hgrp = r8 & 1;
    const int iblk = (r8 >> 1) + 64 * l4;   // 0..255
    const int head = hgrp * 4 + wl;
    const int hf0  = head * FD;
    const int i0   = iblk * BI;
    const int g  = lane >> 4;
    const int lr = lane & 15;
    const int jbase = jc * CH;
    const int jrot  = l4 * 512;             // stagger within chunk per XCD-group

    // stage this block's bitmask slice (16 rows x 64 words = 4 KB)
    #pragma unroll
    for (int u = 0; u < 4; ++u) {
        const int idx = u * 256 + tid;
        const int rr = idx >> 6, w = idx & 63;
        bmLds[rr * 65 + w] = bm[(size_t)(i0 + rr) * 128 + jc * 64 + w];
    }
    __syncthreads();

    const float es1 = es1T[head * NN + i0 + lr];
    const float es2 = es2T[head * NN + i0 + lr];

    floatx4 acc[4] = {};
    floatx4 accd = {};
    short8 ones;
    #pragma unroll
    for (int e = 0; e < 8; ++e) ones[e] = (short)0x3F80;

    auto LD = [&](int t, short8 (&bf)[2][4], uint32_t &m0, uint32_t &m1) {
        const int jl = (jrot + t * JT) & (CH - 1);
        const int j0 = jbase + jl;
        #pragma unroll
        for (int ks = 0; ks < 2; ++ks)
            #pragma unroll
            for (int ni = 0; ni < 4; ++ni)
                bf[ks][ni] = *reinterpret_cast<const short8*>(
                    &whbT[(size_t)(hf0 + ni * 16 + lr) * NN + j0 + ks * 32 + g * 8]);
        const int wi = jl >> 5;
        m0 = bmLds[lr * 65 + wi];
        m1 = bmLds[lr * 65 + wi + 1];
    };
    auto CP = [&](int t, short8 (&bf)[2][4], uint32_t m0, uint32_t m1) {
        const int jl = (jrot + t * JT) & (CH - 1);
        const int j0 = jbase + jl;
        #pragma unroll
        for (int ks = 0; ks < 2; ++ks) {
            const uint32_t b = ((ks ? m1 : m0) >> (g * 8)) & 0xFFu;
            const int jo = head * NN + j0 + ks * 32 + g * 8;
            const float4 e1a = *reinterpret_cast<const float4*>(&ed1T[jo]);
            const float4 e1b = *reinterpret_cast<const float4*>(&ed1T[jo + 4]);
            const float4 e2a = *reinterpret_cast<const float4*>(&ed2T[jo]);
            const float4 e2b = *reinterpret_cast<const float4*>(&ed2T[jo + 4]);
            union { uint32_t wd[4]; short8 s8; } pu;
            pu.wd[0] = packtrunc(fmaxf(es1 * e1a.x, es2 * e2a.x),
                                 fmaxf(es1 * e1a.y, es2 * e2a.y)) & bit2mask(b, 0);
            pu.wd[1] = packtrunc(fmaxf(es1 * e1a.z, es2 * e2a.z),
                                 fmaxf(es1 * e1a.w, es2 * e2a.w)) & bit2mask(b, 1);
            pu.wd[2] = packtrunc(fmaxf(es1 * e1b.x, es2 * e2b.x),
                                 fmaxf(es1 * e1b.y, es2 * e2b.y)) & bit2mask(b, 2);
            pu.wd[3] = packtrunc(fmaxf(es1 * e1b.z, es2 * e2b.z),
                                 fmaxf(es1 * e1b.w, es2 * e2b.w)) & bit2mask(b, 3);
            #pragma unroll
            for (int ni = 0; ni < 4; ++ni)
                acc[ni] = __builtin_amdgcn_mfma_f32_16x16x32_bf16(
                    pu.s8, bf[ks][ni], acc[ni], 0, 0, 0);
            accd = __builtin_amdgcn_mfma_f32_16x16x32_bf16(pu.s8, ones, accd, 0, 0, 0);
        }
    };

    // 2-stage software pipeline: named register sets, static indexing
    short8 bfA[2][4], bfB[2][4];
    uint32_t mA0, mA1, mB0, mB1;
    LD(0, bfA, mA0, mA1);
    for (int t = 0; t < NT2; t += 2) {
        LD(t + 1, bfB, mB0, mB1);
        CP(t, bfA, mA0, mA1);
        if (t + 2 < NT2) LD(t + 2, bfA, mA0, mA1);
        CP(t + 1, bfB, mB0, mB1);
    }

    // epilogue: partial num/den stores
    #pragma unroll
    for (int ni = 0; ni < 4; ++ni)
        #pragma unroll
        for (int r = 0; r < 4; ++r)
            numP[((size_t)jc * NN + i0 + g * 4 + r) * HFD + hf0 + ni * 16 + lr] =
                acc[ni][r];
    if (lr == 0) {
        #pragma unroll
        for (int r = 0; r < 4; ++r)
            denP[((size_t)jc * NH + head) * NN + i0 + g * 4 + r] = accd[r];
    }
}

// ---- k4: combine 2 chunk partials, normalize, add bias ----
__global__ __launch_bounds__(256) void k4_reduce(
        const float* __restrict__ numP, const float* __restrict__ denP,
        const float* __restrict__ bias, float* __restrict__ out) {
    const int idx = blockIdx.x * 256 + threadIdx.x;
    const int e0 = idx * 4;
    const int i  = e0 >> 9;
    const int hf = e0 & 511;
    const int hd = hf >> 6;
    float4 s = make_float4(0.f, 0.f, 0.f, 0.f);
    float d = 0.f;
    #pragma unroll
    for (int c = 0; c < NC2; ++c) {
        const float4 v = *reinterpret_cast<const float4*>(&numP[((size_t)c * NN + i) * HFD + hf]);
        s.x += v.x; s.y += v.y; s.z += v.z; s.w += v.w;
        d += denP[((size_t)c * NH + hd) * NN + i];
    }
    const float inv = 1.0f / d;
    const float4 b = *reinterpret_cast<const float4*>(&bias[hf]);
    float4 o;
    o.x = s.x * inv + b.x; o.y = s.y * inv + b.y;
    o.z = s.z * inv + b.z; o.w = s.w * inv + b.w;
    *reinterpret_cast<float4*>(&out[(size_t)i * HFD + hf]) = o;
}

extern "C" void kernel_launch(void* const* d_in, const int* in_sizes, int n_in,
                              void* d_out, int out_size, void* d_ws, size_t ws_size,
                              hipStream_t stream) {
    const float* hmat  = (const float*)d_in[0];
    const int*   adj   = (const int*)d_in[1];
    const float* Wmat  = (const float*)d_in[2];
    const float* a_src = (const float*)d_in[3];
    const float* a_dst = (const float*)d_in[4];
    const float* bias  = (const float*)d_in[5];
    float* out = (float*)d_out;

    char* ws = (char*)d_ws;
    unsigned short* whbT = (unsigned short*)ws;               // 4 MiB
    float* esrcT = (float*)(ws + (4u << 20));                 // 6 x 128 KiB
    float* edstT = esrcT + NH * NN;
    float* es1T  = edstT + NH * NN;
    float* es2T  = es1T + NH * NN;
    float* ed1T  = es2T + NH * NN;
    float* ed2T  = ed1T + NH * NN;
    uint32_t* bmk = (uint32_t*)(ed2T + NH * NN);              // 2 MiB bitmask
    float* numP = (float*)(bmk + (size_t)(NN / 32) * NN);     // 16 MiB partials
    float* denP = numP + (size_t)NC2 * NN * HFD;              // 256 KiB
    // prep buffers alias numP (dead after k1; k3 overwrites before k4 reads)
    unsigned short* h_hi = (unsigned short*)numP;             // 2 MiB
    unsigned short* h_lo = h_hi + (size_t)NN * KIN;           // 2 MiB
    unsigned short* wt_hi = h_lo + (size_t)NN * KIN;          // 256 KiB
    unsigned short* wt_lo = wt_hi + (size_t)KIN * HFD;        // 256 KiB

    k0_prep<<<dim3(3584), 256, 0, stream>>>(hmat, Wmat, adj, h_hi, h_lo, wt_hi, wt_lo, bmk);
    k1_front<<<dim3(64, 8), 256, 0, stream>>>(h_hi, h_lo, wt_hi, wt_lo, a_src, a_dst,
                                              whbT, esrcT, edstT);
    k2_tables<<<dim3(NH), 256, 0, stream>>>(esrcT, edstT, es1T, es2T, ed1T, ed2T);
    k3_attn<<<dim3(1024), 256, 0, stream>>>(bmk, whbT, es1T, es2T, ed1T, ed2T, numP, denP);
    k4_reduce<<<dim3((NN * HFD / 4) / 256), 256, 0, stream>>>(numP, denP, bias, out);
}